// Round 12
// baseline (293.872 us; speedup 1.0000x reference)
//
#include <hip/hip_runtime.h>
#include <stdint.h>

#define MM 16384
#define KK 2048
#define NN 2048
#define GG 64
#define EPSV 1e-5f
#define NT 32           // K tiles of 64

typedef short short8 __attribute__((ext_vector_type(8)));
typedef float floatx4 __attribute__((ext_vector_type(4)));

__device__ __forceinline__ uint16_t f2bf(float f) {
  uint32_t u = __float_as_uint(f);
  u = (u + 0x7fffu + ((u >> 16) & 1u)) >> 16;
  return (uint16_t)u;
}

__global__ void cvt_f32_to_bf16(const float* __restrict__ src,
                                uint16_t* __restrict__ dst, int n4) {
  int stride = gridDim.x * blockDim.x;
  for (int i = blockIdx.x * blockDim.x + threadIdx.x; i < n4; i += stride) {
    float4 v = reinterpret_cast<const float4*>(src)[i];
    ushort4 o;
    o.x = f2bf(v.x); o.y = f2bf(v.y); o.z = f2bf(v.z); o.w = f2bf(v.w);
    reinterpret_cast<ushort4*>(dst)[i] = o;
  }
}

__device__ __forceinline__ void gload_lds16(const void* g, void* l) {
  __builtin_amdgcn_global_load_lds(
      (const __attribute__((address_space(1))) void*)g,
      (__attribute__((address_space(3))) void*)l, 16, 0, 0);
}

// DPP 16-lane row reduction (pure VALU, lanes [lhi*16..lhi*16+15] = DPP row).
#define ROR_ADD(v, n)                                                      \
  v += __int_as_float(__builtin_amdgcn_update_dpp(                         \
      0, __float_as_int(v), 0x120 + (n), 0xF, 0xF, true))
#define ROW_REDUCE(v) { ROR_ADD(v, 1); ROR_ADD(v, 2); ROR_ADD(v, 4); ROR_ADD(v, 8); }

// r12: B DIRECT GLOBAL->REGISTER (no B LDS path). r2-r11 established the
// per-K-tile resource budget: MFMA 2480cyc/CU, LDS 2750cyc/CU (192KB frag
// reads + 64KB DMA writes) -> co-critical pipes, MfmaUtil pinned ~33-35%
// regardless of schedule. Only REMOVING LDS traffic changes the ratio.
// W is 8MB bf16; with tn=bid&7 each XCD's 256-col slab is 1MB, L2-resident.
// B frags load straight to VGPRs: 8x global_load_dwordx4 /wave/K-tile,
// perfectly coalesced (lanes (llo,lhi) tile 16 full 64B lines), double-set
// (bX/bY) prefetched 1 tile ahead; tile-end barrier drain puts the vmcnt
// wait after the MFMA section. LDS now A-only: reads 128KB(-33%), writes
// 32KB(-50%), footprint 64KB. New budget: LDS ~1750 vs MFMA 2480 ->
// matrix pipe is the longest pole.
__global__ __launch_bounds__(512, 2)
void gemm_gn_silu_br(const uint16_t* __restrict__ xb,  // M x K bf16
                     const uint16_t* __restrict__ wb,  // N x K bf16
                     const float* __restrict__ bias,   // N
                     const float* __restrict__ gnw,    // G
                     const float* __restrict__ gnb,    // G
                     const float* __restrict__ mw,     // N
                     float* __restrict__ out) {        // M x N f32
  extern __shared__ char lds[];   // 65536 = 2 bufs x 32KB (A only)

  int bid = blockIdx.x;
  int tn = bid & 7;           // XCD-pinned W slab (1MB, L2-resident)
  int tm = bid >> 3;          // 0..63
  int row0 = tm * 256;
  int col0 = tn * 256;

  int t = threadIdx.x;
  int lane = t & 63;
  int wid = t >> 6;
  int wm = wid >> 2, wn = wid & 3;   // 2x4 wave grid
  int llo = lane & 15, lhi = lane >> 4;
  int sw = (llo & 7) << 4;

  const char* xgb = (const char*)xb + (size_t)row0 * (KK * 2);

  // ---- A staging: 4 gloads/thread/tile; dest linear, src pre-swizzled ----
  const char* gaSrc[4];
  int oq[4];
  #pragma unroll
  for (int q = 0; q < 4; ++q) {
    int o = q * 8192 + t * 16;        // 0..32752
    int row = o >> 7;                 // 0..255 (A row, 128B each)
    int spb = (o & 127) ^ ((row & 7) << 4);
    gaSrc[q] = xgb + (size_t)row * (KK * 2) + spb;
    oq[q] = o;
  }
#define STAGEA(BUF, KT)                                                    \
  {                                                                        \
    _Pragma("unroll") for (int q = 0; q < 4; ++q)                          \
        gload_lds16(gaSrc[q] + (size_t)(KT)*128,                           \
                    lds + (BUF)*32768 + oq[q]);                            \
  }

  // ---- A fragment read offsets (swizzle fragment-invariant) ----
  uint32_t aOff[2][2];
  #pragma unroll
  for (int buf = 0; buf < 2; ++buf)
    #pragma unroll
    for (int kk = 0; kk < 2; ++kk)
      aOff[buf][kk] = buf * 32768u + (uint32_t)(wm * 128 + llo) * 128u +
                      (uint32_t)((kk * 64 + lhi * 16) ^ sw);

  // ---- B direct-load pointers: col = col0 + wn*64 + ni*16 + llo ----
  const char* wptr[4];
  #pragma unroll
  for (int ni = 0; ni < 4; ++ni)
    wptr[ni] = (const char*)wb +
               (size_t)(col0 + wn * 64 + ni * 16 + llo) * (KK * 2) +
               lhi * 16;
#define LDB(bq, KT)                                                        \
  {                                                                        \
    _Pragma("unroll") for (int ni = 0; ni < 4; ++ni)                       \
        _Pragma("unroll") for (int kk = 0; kk < 2; ++kk)                   \
            bq[ni][kk] = *(const short8*)(wptr[ni] + (size_t)(KT)*128 +    \
                                          kk * 64);                        \
  }

  short8 a[4][2], bX[4][2], bY[4][2];
  floatx4 acc[8][4] = {};

#define RDA(buf, mh)                                                       \
  {                                                                        \
    _Pragma("unroll") for (int kk = 0; kk < 2; ++kk)                       \
        _Pragma("unroll") for (int mi2 = 0; mi2 < 4; ++mi2)                \
            a[mi2][kk] = *(const short8*)(lds + aOff[buf][kk] +            \
                                          (mh)*8192 + mi2 * 2048);         \
  }
  // kk OUTER: 16 independent MFMAs between accumulator reuse.
#define MFMAH(mh, bq)                                                      \
  {                                                                        \
    _Pragma("unroll") for (int kk = 0; kk < 2; ++kk)                       \
        _Pragma("unroll") for (int mi2 = 0; mi2 < 4; ++mi2)                \
            _Pragma("unroll") for (int ni = 0; ni < 4; ++ni)               \
                acc[(mh)*4 + mi2][ni] =                                    \
                    __builtin_amdgcn_mfma_f32_16x16x32_bf16(               \
                        a[mi2][kk], bq[ni][kk],                            \
                        acc[(mh)*4 + mi2][ni], 0, 0, 0);                   \
  }

  // Prologue: stage A(0), load B(0); drain; sync.
  STAGEA(0, 0);
  LDB(bX, 0);
  __syncthreads();

  // 2 tiles per iteration for static bX/bY names (rule #20).
  #pragma unroll 1
  for (int it = 0; it < NT / 2; ++it) {
    int k0 = 2 * it;
    // ---- tile k0 (buf 0, uses bX) ----
    STAGEA(1, k0 + 1);
    LDB(bY, k0 + 1);
    RDA(0, 0);
    __builtin_amdgcn_s_setprio(1);
    MFMAH(0, bX);
    RDA(0, 1);
    MFMAH(1, bX);
    __builtin_amdgcn_s_setprio(0);
    __syncthreads();
    // ---- tile k0+1 (buf 1, uses bY) ----
    if (k0 + 2 < NT) {
      STAGEA(0, k0 + 2);
      LDB(bX, k0 + 2);
    }
    RDA(1, 0);
    __builtin_amdgcn_s_setprio(1);
    MFMAH(0, bY);
    RDA(1, 1);
    MFMAH(1, bY);
    __builtin_amdgcn_s_setprio(0);
    __syncthreads();
  }

  // ---- fused epilogue: bias + GroupNorm(32) + SiLU * mw * SiLU ----
  // C/D frag: col = cb + ni*16 + llo ; row = rb + mi*16 + lhi*4 + j
  int cb = col0 + wn * 64;   // 2 groups of 32 per wave
  int rb = row0 + wm * 128;

  float bias_v[4], mw_v[4];
  #pragma unroll
  for (int ni = 0; ni < 4; ++ni) {
    int c = cb + ni * 16 + llo;
    bias_v[ni] = bias[c];
    mw_v[ni] = mw[c];
  }
  #pragma unroll
  for (int mi = 0; mi < 8; ++mi)
    #pragma unroll
    for (int ni = 0; ni < 4; ++ni)
      #pragma unroll
      for (int j = 0; j < 4; ++j)
        acc[mi][ni][j] += bias_v[ni];

  #pragma unroll
  for (int mi = 0; mi < 8; ++mi) {
    #pragma unroll
    for (int gp = 0; gp < 2; ++gp) {
      int g = (cb >> 5) + gp;
      float gw = gnw[g], gb = gnb[g];
      float s[4], ss[4];
      #pragma unroll
      for (int j = 0; j < 4; ++j) {
        float a0 = acc[mi][2 * gp][j];
        float a1 = acc[mi][2 * gp + 1][j];
        s[j] = a0 + a1;
        ss[j] = a0 * a0 + a1 * a1;
      }
      #pragma unroll
      for (int j = 0; j < 4; ++j) {
        ROW_REDUCE(s[j]);
        ROW_REDUCE(ss[j]);
      }
      #pragma unroll
      for (int j = 0; j < 4; ++j) {
        float mean = s[j] * (1.0f / 32.0f);
        float var  = ss[j] * (1.0f / 32.0f) - mean * mean;
        float rstd = rsqrtf(var + EPSV);
        int r = rb + mi * 16 + lhi * 4 + j;
        #pragma unroll
        for (int nn = 0; nn < 2; ++nn) {
          int ni = 2 * gp + nn;
          float v = (acc[mi][ni][j] - mean) * rstd * gw + gb;
          v = v / (1.0f + __expf(-v));   // SiLU
          v = v * mw_v[ni];
          v = v / (1.0f + __expf(-v));   // SiLU
          out[(size_t)r * NN + (cb + ni * 16 + llo)] = v;
        }
      }
    }
  }
}

// ---------------- naive f32 fallback (only if ws too small) ----------------
__global__ void naive_gemm(const float* __restrict__ x, const float* __restrict__ w,
                           const float* __restrict__ bias, float* __restrict__ out) {
  size_t idx = (size_t)blockIdx.x * 256 + threadIdx.x;
  int m = (int)(idx >> 11);
  int n = (int)(idx & 2047);
  const float* xr = x + (size_t)m * KK;
  const float* wr = w + (size_t)n * KK;
  float s = bias[n];
  for (int k = 0; k < KK; k += 4)
    s += xr[k] * wr[k] + xr[k+1] * wr[k+1] + xr[k+2] * wr[k+2] + xr[k+3] * wr[k+3];
  out[idx] = s;
}

__global__ void naive_post(float* __restrict__ out, const float* __restrict__ gnw,
                           const float* __restrict__ gnb, const float* __restrict__ mw) {
  size_t idx = (size_t)blockIdx.x * 256 + threadIdx.x;  // M*G
  int m = (int)(idx >> 6);
  int g = (int)(idx & 63);
  float* p = out + (size_t)m * NN + g * 32;
  float s = 0.f, ss = 0.f;
  for (int j = 0; j < 32; ++j) { float v = p[j]; s += v; ss += v * v; }
  float mean = s * (1.0f / 32.0f);
  float var  = ss * (1.0f / 32.0f) - mean * mean;
  float rstd = rsqrtf(var + EPSV);
  float gw = gnw[g], gb = gnb[g];
  for (int j = 0; j < 32; ++j) {
    float v = (p[j] - mean) * rstd * gw + gb;
    v = v / (1.0f + __expf(-v));
    v = v * mw[g * 32 + j];
    v = v / (1.0f + __expf(-v));
    p[j] = v;
  }
}

extern "C" void kernel_launch(void* const* d_in, const int* in_sizes, int n_in,
                              void* d_out, int out_size, void* d_ws, size_t ws_size,
                              hipStream_t stream) {
  const float* x    = (const float*)d_in[0];
  const float* wgt  = (const float*)d_in[1];
  const float* bias = (const float*)d_in[2];
  const float* gnw  = (const float*)d_in[3];
  const float* gnb  = (const float*)d_in[4];
  const float* mwp  = (const float*)d_in[5];
  float* out = (float*)d_out;

  size_t need = ((size_t)MM * KK + (size_t)NN * KK) * 2;
  if (ws_size >= need) {
    uint16_t* xbf = (uint16_t*)d_ws;
    uint16_t* wbf = xbf + (size_t)MM * KK;
    cvt_f32_to_bf16<<<2048, 256, 0, stream>>>(x, xbf, (MM * KK) / 4);
    cvt_f32_to_bf16<<<512, 256, 0, stream>>>(wgt, wbf, (NN * KK) / 4);
    (void)hipFuncSetAttribute((const void*)gemm_gn_silu_br,
                              hipFuncAttributeMaxDynamicSharedMemorySize, 65536);
    gemm_gn_silu_br<<<512, 512, 65536, stream>>>(xbf, wbf, bias, gnw, gnb, mwp, out);
  } else {
    naive_gemm<<<(MM * (size_t)NN) / 256, 256, 0, stream>>>(x, wgt, bias, out);
    naive_post<<<(MM * GG) / 256, 256, 0, stream>>>(out, gnw, gnb, mwp);
  }
}